// Round 2
// baseline (223.118 us; speedup 1.0000x reference)
//
#include <hip/hip_runtime.h>
#include <cstdint>

#define EPSN 1e-12f
static constexpr int B_ROWS = 1024;
static constexpr int IN_DIM = 512;
static constexpr int OUT_DIM = 64000;

typedef __attribute__((ext_vector_type(8))) short bf16x8;
typedef __attribute__((ext_vector_type(4))) float f32x4;

__device__ __forceinline__ unsigned short f2bf(float f) {
  uint32_t u = __builtin_bit_cast(uint32_t, f);
  u += 0x7fffu + ((u >> 16) & 1u);   // round-to-nearest-even
  return (unsigned short)(u >> 16);
}

__device__ __forceinline__ float wave_sum(float v) {
#pragma unroll
  for (int off = 32; off; off >>= 1) v += __shfl_xor(v, off);
  return v;
}

__device__ __forceinline__ void async16(const void* g, void* l) {
  __builtin_amdgcn_global_load_lds((const __attribute__((address_space(1))) uint32_t*)g,
                                   (__attribute__((address_space(3))) uint32_t*)l, 16, 0, 0);
}

// --- kernel 1: weight row L2-normalize; write wn (f32, output 1) + wn bf16 to ws ---
__global__ void wnorm_kernel(const float* __restrict__ Wg, float* __restrict__ wnOut,
                             unsigned short* __restrict__ wbf, int useBf) {
  int lane = threadIdx.x & 63;
  int row = blockIdx.x * 4 + (threadIdx.x >> 6);
  const float* src = Wg + (size_t)row * IN_DIM + lane * 8;
  float4 a = *(const float4*)src;
  float4 b = *(const float4*)(src + 4);
  float ss = a.x * a.x;
  ss = fmaf(a.y, a.y, ss); ss = fmaf(a.z, a.z, ss); ss = fmaf(a.w, a.w, ss);
  ss = fmaf(b.x, b.x, ss); ss = fmaf(b.y, b.y, ss); ss = fmaf(b.z, b.z, ss);
  ss = fmaf(b.w, b.w, ss);
  ss = wave_sum(ss);
  float inv = 1.0f / fmaxf(sqrtf(ss), EPSN);
  float4 wa, wb;
  wa.x = a.x * inv; wa.y = a.y * inv; wa.z = a.z * inv; wa.w = a.w * inv;
  wb.x = b.x * inv; wb.y = b.y * inv; wb.z = b.z * inv; wb.w = b.w * inv;
  float* dst = wnOut + (size_t)row * IN_DIM + lane * 8;
  *(float4*)dst = wa;
  *(float4*)(dst + 4) = wb;
  if (useBf) {
    uint4 u;
    u.x = (uint32_t)f2bf(wa.x) | ((uint32_t)f2bf(wa.y) << 16);
    u.y = (uint32_t)f2bf(wa.z) | ((uint32_t)f2bf(wa.w) << 16);
    u.z = (uint32_t)f2bf(wb.x) | ((uint32_t)f2bf(wb.y) << 16);
    u.w = (uint32_t)f2bf(wb.z) | ((uint32_t)f2bf(wb.w) << 16);
    *(uint4*)(wbf + (size_t)row * IN_DIM + lane * 8) = u;
  }
}

// --- kernel 2: x row norms (for epilogue) + raw-x bf16 cast to ws ---
__global__ void xprep_kernel(const float* __restrict__ X, float* __restrict__ norms,
                             unsigned short* __restrict__ xbf) {
  int lane = threadIdx.x & 63;
  int row = blockIdx.x * 4 + (threadIdx.x >> 6);
  const float* src = X + (size_t)row * IN_DIM + lane * 8;
  float4 a = *(const float4*)src;
  float4 b = *(const float4*)(src + 4);
  float ss = a.x * a.x;
  ss = fmaf(a.y, a.y, ss); ss = fmaf(a.z, a.z, ss); ss = fmaf(a.w, a.w, ss);
  ss = fmaf(b.x, b.x, ss); ss = fmaf(b.y, b.y, ss); ss = fmaf(b.z, b.z, ss);
  ss = fmaf(b.w, b.w, ss);
  ss = wave_sum(ss);
  if (lane == 0) norms[row] = sqrtf(ss);
  uint4 u;
  u.x = (uint32_t)f2bf(a.x) | ((uint32_t)f2bf(a.y) << 16);
  u.y = (uint32_t)f2bf(a.z) | ((uint32_t)f2bf(a.w) << 16);
  u.z = (uint32_t)f2bf(b.x) | ((uint32_t)f2bf(b.y) << 16);
  u.w = (uint32_t)f2bf(b.z) | ((uint32_t)f2bf(b.w) << 16);
  *(uint4*)(xbf + (size_t)row * IN_DIM + lane * 8) = u;
}

// --- kernel 3: exact f32 dot at (row, label[row]) ---
__global__ void labelfix_kernel(const float* __restrict__ X, const int* __restrict__ label,
                                const float* __restrict__ wn, float* __restrict__ fixdot) {
  int lane = threadIdx.x & 63;
  int row = blockIdx.x * 4 + (threadIdx.x >> 6);
  int lab = label[row];
  const float* xs = X + (size_t)row * IN_DIM + lane * 8;
  const float* wsrc = wn + (size_t)lab * IN_DIM + lane * 8;
  float4 xa = *(const float4*)xs, xb = *(const float4*)(xs + 4);
  float4 wa = *(const float4*)wsrc, wb = *(const float4*)(wsrc + 4);
  float d = xa.x * wa.x;
  d = fmaf(xa.y, wa.y, d); d = fmaf(xa.z, wa.z, d); d = fmaf(xa.w, wa.w, d);
  d = fmaf(xb.x, wb.x, d); d = fmaf(xb.y, wb.y, d); d = fmaf(xb.z, wb.z, d);
  d = fmaf(xb.w, wb.w, d);
  d = wave_sum(d);
  if (lane == 0) fixdot[row] = d;
}

// --- kernel 4: bf16 MFMA GEMM (M=1024,N=64000,K=512) + margin epilogue ---
// 128x256 tile, BK=32, 8 waves (2Mx4N), each wave 64x64 = 4x4 frags of 16x16x32.
// 2-phase double-buffered: stage(next) issued before compute(cur); counted
// s_waitcnt vmcnt(3) keeps the 3 prefetch loads in flight ACROSS the barrier.
// LDS XOR-swizzle byte ^= ((row>>1)&7)<<4 via pre-swizzled GLOBAL source
// (LDS dest linear, rule #21).
template <bool BF16B>
__global__ __launch_bounds__(512, 2) void gemm_epi_kernel(
    const unsigned short* __restrict__ Abf, const unsigned short* __restrict__ Bbf,
    const float* __restrict__ Bf32, const float* __restrict__ norms,
    const float* __restrict__ fixdot, const int* __restrict__ label,
    const float* __restrict__ mArr, float* __restrict__ out0) {
  __shared__ uint4 smem4[3072];  // 48 KiB: A0[0,8K) A1[8K,16K) B0[16K,32K) B1[32K,48K)
  char* smem = (char*)smem4;

  int t = threadIdx.x;
  // XCD-bijective swizzle: 2000 blocks = 8 * 250. The 8 M-tiles sharing one
  // B-panel are consecutive wk on one XCD -> B read from HBM ~once.
  int flat = blockIdx.x;
  int xcd = flat & 7;
  int wk = (flat >> 3) + xcd * 250;
  int mT = wk & 7, nT = wk >> 3;
  int rowA0 = mT * 128, rowB0 = nT * 256;

  int lane = t & 63;
  int wid = t >> 6;
  int wm = wid >> 2, wn2 = wid & 3;   // 2M x 4N wave grid
  int rl = lane & 15, sl = lane >> 4;

  // staging maps (inverse of LDS read swizzle), loop-invariant
  int Wa = t * 16;
  int lineA = Wa >> 7;
  int xa = ((Wa >> 4) & 7) ^ (lineA & 7);
  int rA = lineA * 2 + (xa >> 2), sA = xa & 3;
  const unsigned short* aSrc = Abf + (size_t)(rowA0 + rA) * IN_DIM + sA * 8;

  int rB[2], sB[2];
#pragma unroll
  for (int c = 0; c < 2; ++c) {
    int W = (t + c * 512) * 16;
    int line = W >> 7;
    int xx = ((W >> 4) & 7) ^ (line & 7);
    rB[c] = line * 2 + (xx >> 2);
    sB[c] = xx & 3;
  }
  const unsigned short* bSrc0 = Bbf + (size_t)(rowB0 + rB[0]) * IN_DIM + sB[0] * 8;
  const unsigned short* bSrc1 = Bbf + (size_t)(rowB0 + rB[1]) * IN_DIM + sB[1] * 8;

  f32x4 acc[4][4];
#pragma unroll
  for (int i = 0; i < 4; ++i)
#pragma unroll
    for (int j = 0; j < 4; ++j) acc[i][j] = (f32x4){0.f, 0.f, 0.f, 0.f};

  if constexpr (BF16B) {
    // prologue: stage buf0 (3 loads/thread, stay in flight)
    async16(aSrc, smem + Wa);
    async16(bSrc0, smem + 16384 + t * 16);
    async16(bSrc1, smem + 16384 + (t + 512) * 16);

#pragma unroll 1
    for (int kk = 0; kk < 16; ++kk) {
      int cur = kk & 1;
      if (kk < 15) {
        int k0 = (kk + 1) * 32;
        int nxt = cur ^ 1;
        async16(aSrc + k0, smem + nxt * 8192 + Wa);
        async16(bSrc0 + k0, smem + 16384 + nxt * 16384 + t * 16);
        async16(bSrc1 + k0, smem + 16384 + nxt * 16384 + (t + 512) * 16);
        // older 3 loads (current buf) complete; 3 prefetch stay in flight
        asm volatile("s_waitcnt vmcnt(3)" ::: "memory");
      } else {
        asm volatile("s_waitcnt vmcnt(0)" ::: "memory");
      }
      __builtin_amdgcn_s_barrier();
      __builtin_amdgcn_sched_barrier(0);

      const char* aBase = smem + cur * 8192;
      const char* bBase = smem + 16384 + cur * 16384;
      bf16x8 av[4], bv[4];
#pragma unroll
      for (int i = 0; i < 4; ++i) {
        int r = wm * 64 + i * 16 + rl;
        av[i] = *(const bf16x8*)(aBase + ((r * 64 + sl * 16) ^ (((r >> 1) & 7) << 4)));
      }
#pragma unroll
      for (int j = 0; j < 4; ++j) {
        int r = wn2 * 64 + j * 16 + rl;
        bv[j] = *(const bf16x8*)(bBase + ((r * 64 + sl * 16) ^ (((r >> 1) & 7) << 4)));
      }
#pragma unroll
      for (int i = 0; i < 4; ++i)
#pragma unroll
        for (int j = 0; j < 4; ++j)
          acc[i][j] = __builtin_amdgcn_mfma_f32_16x16x32_bf16(av[i], bv[j], acc[i][j], 0, 0, 0);
      // all waves done reading cur buf before next iter overwrites it
      asm volatile("s_waitcnt lgkmcnt(0)" ::: "memory");
      __builtin_amdgcn_s_barrier();
      __builtin_amdgcn_sched_barrier(0);
    }
  } else {
    // fallback: ws too small for bf16 wn; single-buffer, reg-stage B from f32
#pragma unroll 1
    for (int kk = 0; kk < 16; ++kk) {
      int k0 = kk * 32;
      async16(aSrc + k0, smem + Wa);
#pragma unroll
      for (int c = 0; c < 2; ++c) {
        int blk = t + c * 512;
        int r = blk >> 2, s = blk & 3;
        const float* srcp = Bf32 + (size_t)(rowB0 + r) * IN_DIM + k0 + s * 8;
        float4 f0 = *(const float4*)srcp;
        float4 f1 = *(const float4*)(srcp + 4);
        uint4 u;
        u.x = (uint32_t)f2bf(f0.x) | ((uint32_t)f2bf(f0.y) << 16);
        u.y = (uint32_t)f2bf(f0.z) | ((uint32_t)f2bf(f0.w) << 16);
        u.z = (uint32_t)f2bf(f1.x) | ((uint32_t)f2bf(f1.y) << 16);
        u.w = (uint32_t)f2bf(f1.z) | ((uint32_t)f2bf(f1.w) << 16);
        int off = 16384 + ((r * 64 + s * 16) ^ (((r >> 1) & 7) << 4));
        *(uint4*)(smem + off) = u;
      }
      __syncthreads();
      bf16x8 av[4], bv[4];
#pragma unroll
      for (int i = 0; i < 4; ++i) {
        int r = wm * 64 + i * 16 + rl;
        av[i] = *(const bf16x8*)(smem + ((r * 64 + sl * 16) ^ (((r >> 1) & 7) << 4)));
      }
#pragma unroll
      for (int j = 0; j < 4; ++j) {
        int r = wn2 * 64 + j * 16 + rl;
        bv[j] = *(const bf16x8*)(smem + 16384 + ((r * 64 + sl * 16) ^ (((r >> 1) & 7) << 4)));
      }
#pragma unroll
      for (int i = 0; i < 4; ++i)
#pragma unroll
        for (int j = 0; j < 4; ++j)
          acc[i][j] = __builtin_amdgcn_mfma_f32_16x16x32_bf16(av[i], bv[j], acc[i][j], 0, 0, 0);
      __syncthreads();
    }
  }

  // epilogue: out = rawdot, except at (r, label[r]) where the exact f32 dot decides
  float mm = mArr[0];
  float cm = cosf(mm), sm = sinf(mm);
  int rowb = rowA0 + wm * 64, colb = rowB0 + wn2 * 64;
#pragma unroll
  for (int i = 0; i < 4; ++i) {
    int lab4[4]; float n4[4], f4[4];
#pragma unroll
    for (int q = 0; q < 4; ++q) {
      int R = rowb + i * 16 + sl * 4 + q;
      lab4[q] = label[R];
      n4[q] = norms[R];
      f4[q] = fixdot[R];
    }
#pragma unroll
    for (int j = 0; j < 4; ++j) {
      int Cc = colb + j * 16 + rl;
      f32x4 v = acc[i][j];
#pragma unroll
      for (int q = 0; q < 4; ++q) {
        float val = v[q];
        if (Cc == lab4[q]) {
          float n = n4[q];
          float c = f4[q] / fmaxf(n, EPSN);
          val = (c > 0.f) ? n * (c * cm - sqrtf(fmaxf(1.f - c * c, 0.f)) * sm) : f4[q];
        }
        out0[(size_t)(rowb + i * 16 + sl * 4 + q) * OUT_DIM + Cc] = val;
      }
    }
  }
}

extern "C" void kernel_launch(void* const* d_in, const int* in_sizes, int n_in,
                              void* d_out, int out_size, void* d_ws, size_t ws_size,
                              hipStream_t stream) {
  const float* x = (const float*)d_in[0];
  const int* label = (const int*)d_in[1];
  const float* weight = (const float*)d_in[2];
  const float* mArr = (const float*)d_in[4];  // d_in[3] = s, unused by normfree output

  float* out0 = (float*)d_out;                               // [1024, 64000]
  float* wnOut = out0 + (size_t)B_ROWS * OUT_DIM;            // [64000, 512]

  char* ws = (char*)d_ws;
  float* norms = (float*)ws;                                 // 4 KiB
  float* fixdot = (float*)(ws + 4096);                       // 4 KiB
  unsigned short* xbf = (unsigned short*)(ws + 8192);        // 1 MiB
  unsigned short* wbf = (unsigned short*)(ws + 8192 + 2ull * B_ROWS * IN_DIM);
  size_t need = 8192 + 2ull * B_ROWS * IN_DIM + 2ull * OUT_DIM * IN_DIM;
  bool useBf = ws_size >= need;

  wnorm_kernel<<<OUT_DIM / 4, 256, 0, stream>>>(weight, wnOut, wbf, useBf ? 1 : 0);
  xprep_kernel<<<B_ROWS / 4, 256, 0, stream>>>(x, norms, xbf);
  labelfix_kernel<<<B_ROWS / 4, 256, 0, stream>>>(x, label, wnOut, fixdot);
  if (useBf)
    gemm_epi_kernel<true><<<2000, 512, 0, stream>>>(xbf, wbf, wnOut, norms, fixdot,
                                                    label, mArr, out0);
  else
    gemm_epi_kernel<false><<<2000, 512, 0, stream>>>(xbf, wbf, wnOut, norms, fixdot,
                                                     label, mArr, out0);
}

// Round 3
// 199.032 us; speedup vs baseline: 1.1210x; 1.1210x over previous
//
#include <hip/hip_runtime.h>
#include <cstdint>

#define EPSN 1e-12f
static constexpr int B_ROWS = 1024;
static constexpr int IN_DIM = 512;
static constexpr int OUT_DIM = 64000;

typedef __attribute__((ext_vector_type(8))) short bf16x8;
typedef __attribute__((ext_vector_type(4))) float f32x4;

__device__ __forceinline__ unsigned short f2bf(float f) {
  uint32_t u = __builtin_bit_cast(uint32_t, f);
  u += 0x7fffu + ((u >> 16) & 1u);   // round-to-nearest-even
  return (unsigned short)(u >> 16);
}

__device__ __forceinline__ float wave_sum(float v) {
#pragma unroll
  for (int off = 32; off; off >>= 1) v += __shfl_xor(v, off);
  return v;
}

__device__ __forceinline__ void async16(const void* g, void* l) {
  __builtin_amdgcn_global_load_lds((const __attribute__((address_space(1))) uint32_t*)g,
                                   (__attribute__((address_space(3))) uint32_t*)l, 16, 0, 0);
}

// --- kernel 1: weight row L2-normalize; write wn (f32, output 1) + wn bf16 to ws ---
__global__ void wnorm_kernel(const float* __restrict__ Wg, float* __restrict__ wnOut,
                             unsigned short* __restrict__ wbf, int useBf) {
  int lane = threadIdx.x & 63;
  int row = blockIdx.x * 4 + (threadIdx.x >> 6);
  const float* src = Wg + (size_t)row * IN_DIM + lane * 8;
  float4 a = *(const float4*)src;
  float4 b = *(const float4*)(src + 4);
  float ss = a.x * a.x;
  ss = fmaf(a.y, a.y, ss); ss = fmaf(a.z, a.z, ss); ss = fmaf(a.w, a.w, ss);
  ss = fmaf(b.x, b.x, ss); ss = fmaf(b.y, b.y, ss); ss = fmaf(b.z, b.z, ss);
  ss = fmaf(b.w, b.w, ss);
  ss = wave_sum(ss);
  float inv = 1.0f / fmaxf(sqrtf(ss), EPSN);
  float4 wa, wb;
  wa.x = a.x * inv; wa.y = a.y * inv; wa.z = a.z * inv; wa.w = a.w * inv;
  wb.x = b.x * inv; wb.y = b.y * inv; wb.z = b.z * inv; wb.w = b.w * inv;
  float* dst = wnOut + (size_t)row * IN_DIM + lane * 8;
  *(float4*)dst = wa;
  *(float4*)(dst + 4) = wb;
  if (useBf) {
    uint4 u;
    u.x = (uint32_t)f2bf(wa.x) | ((uint32_t)f2bf(wa.y) << 16);
    u.y = (uint32_t)f2bf(wa.z) | ((uint32_t)f2bf(wa.w) << 16);
    u.z = (uint32_t)f2bf(wb.x) | ((uint32_t)f2bf(wb.y) << 16);
    u.w = (uint32_t)f2bf(wb.z) | ((uint32_t)f2bf(wb.w) << 16);
    *(uint4*)(wbf + (size_t)row * IN_DIM + lane * 8) = u;
  }
}

// --- kernel 2: merged x-prep (norms + bf16 cast) + exact f32 dot at (row,label) ---
__global__ void prep_kernel(const float* __restrict__ X, const int* __restrict__ label,
                            const float* __restrict__ wn, float* __restrict__ norms,
                            float* __restrict__ fixdot, unsigned short* __restrict__ xbf) {
  int lane = threadIdx.x & 63;
  int row = blockIdx.x * 4 + (threadIdx.x >> 6);
  const float* src = X + (size_t)row * IN_DIM + lane * 8;
  float4 a = *(const float4*)src;
  float4 b = *(const float4*)(src + 4);
  uint4 u;
  u.x = (uint32_t)f2bf(a.x) | ((uint32_t)f2bf(a.y) << 16);
  u.y = (uint32_t)f2bf(a.z) | ((uint32_t)f2bf(a.w) << 16);
  u.z = (uint32_t)f2bf(b.x) | ((uint32_t)f2bf(b.y) << 16);
  u.w = (uint32_t)f2bf(b.z) | ((uint32_t)f2bf(b.w) << 16);
  *(uint4*)(xbf + (size_t)row * IN_DIM + lane * 8) = u;
  float ss = a.x * a.x;
  ss = fmaf(a.y, a.y, ss); ss = fmaf(a.z, a.z, ss); ss = fmaf(a.w, a.w, ss);
  ss = fmaf(b.x, b.x, ss); ss = fmaf(b.y, b.y, ss); ss = fmaf(b.z, b.z, ss);
  ss = fmaf(b.w, b.w, ss);
  ss = wave_sum(ss);
  int lab = label[row];
  const float* wsrc = wn + (size_t)lab * IN_DIM + lane * 8;
  float4 wa = *(const float4*)wsrc, wb = *(const float4*)(wsrc + 4);
  float d = a.x * wa.x;
  d = fmaf(a.y, wa.y, d); d = fmaf(a.z, wa.z, d); d = fmaf(a.w, wa.w, d);
  d = fmaf(b.x, wb.x, d); d = fmaf(b.y, wb.y, d); d = fmaf(b.z, wb.z, d);
  d = fmaf(b.w, wb.w, d);
  d = wave_sum(d);
  if (lane == 0) { norms[row] = sqrtf(ss); fixdot[row] = d; }
}

// --- kernel 3: bf16 MFMA GEMM (M=1024,N=64000,K=512) + margin epilogue ---
// m201-style: BM=BN=256, BK=64, 8 waves (2Mx4N), per-wave C = 128x64.
// LDS 128 KiB = 2 K-tile dbuf; each K-tile = 2 sub-stages (K=32): A_s 16K + B_s 16K.
// 16 phases total; phase sigma computes k-slice s of tile kt and issues the
// global_load_lds for sub sigma+3 (3 sub-stages in flight, counted vmcnt(8),
// never drained until the tail). Swizzle: q ^= (r>>1)&3 within each sub-stage
// (2-way bank alias = free), staged via inverse-swizzled GLOBAL source.
template <bool BF16B>
__global__ __launch_bounds__(512, 2) void gemm8_kernel(
    const unsigned short* __restrict__ Abf, const unsigned short* __restrict__ Bbf,
    const float* __restrict__ Bf32, const float* __restrict__ norms,
    const float* __restrict__ fixdot, const int* __restrict__ label,
    const float* __restrict__ mArr, float* __restrict__ out0) {
  __shared__ char smem[131072];  // buf b @ b*65536; A_s @ +s*16384; B_s @ +32768+s*16384

  const int t = threadIdx.x;
  int flat = blockIdx.x;          // 1000 = 8 * 125, bijective XCD swizzle
  int xcd = flat & 7;
  int wk = (flat >> 3) + xcd * 125;
  int mT = wk & 3, nT = wk >> 2;
  int rowA0 = mT * 256, rowB0 = nT * 256;

  int lane = t & 63;
  int wid = t >> 6;
  int wm = wid >> 2, wn2 = wid & 3;   // 2M x 4N wave grid
  int rl = lane & 15, sl = lane >> 4;

  // staging chunk map (inverse swizzle): chunk c = t + 512j -> r = c>>2, q = (c&3)^((r>>1)&3)
  int r0 = t >> 2, q0 = (t & 3) ^ ((r0 >> 1) & 3);
  int r1 = (t + 512) >> 2, q1 = ((t + 512) & 3) ^ ((r1 >> 1) & 3);
  const unsigned short* aP0 = Abf + (size_t)(rowA0 + r0) * IN_DIM + q0 * 8;
  const unsigned short* aP1 = Abf + (size_t)(rowA0 + r1) * IN_DIM + q1 * 8;
  const unsigned short* bP0 = Bbf + (size_t)(rowB0 + r0) * IN_DIM + q0 * 8;
  const unsigned short* bP1 = Bbf + (size_t)(rowB0 + r1) * IN_DIM + q1 * 8;
  const float* bF0 = Bf32 + (size_t)(rowB0 + r0) * IN_DIM + q0 * 8;
  const float* bF1 = Bf32 + (size_t)(rowB0 + r1) * IN_DIM + q1 * 8;

  auto issueSub = [&](int sig) {
    int kt = sig >> 1, s = sig & 1, buf = kt & 1;
    char* aD = smem + buf * 65536 + s * 16384;
    char* bD = aD + 32768;
    int kcol = kt * 64 + s * 32;
    async16(aP0 + kcol, aD + t * 16);
    async16(aP1 + kcol, aD + (t + 512) * 16);
    if constexpr (BF16B) {
      async16(bP0 + kcol, bD + t * 16);
      async16(bP1 + kcol, bD + (t + 512) * 16);
    } else {
      float4 f0 = *(const float4*)(bF0 + kcol);
      float4 f1 = *(const float4*)(bF0 + kcol + 4);
      uint4 u;
      u.x = (uint32_t)f2bf(f0.x) | ((uint32_t)f2bf(f0.y) << 16);
      u.y = (uint32_t)f2bf(f0.z) | ((uint32_t)f2bf(f0.w) << 16);
      u.z = (uint32_t)f2bf(f1.x) | ((uint32_t)f2bf(f1.y) << 16);
      u.w = (uint32_t)f2bf(f1.z) | ((uint32_t)f2bf(f1.w) << 16);
      *(uint4*)(bD + t * 16) = u;
      f0 = *(const float4*)(bF1 + kcol);
      f1 = *(const float4*)(bF1 + kcol + 4);
      u.x = (uint32_t)f2bf(f0.x) | ((uint32_t)f2bf(f0.y) << 16);
      u.y = (uint32_t)f2bf(f0.z) | ((uint32_t)f2bf(f0.w) << 16);
      u.z = (uint32_t)f2bf(f1.x) | ((uint32_t)f2bf(f1.y) << 16);
      u.w = (uint32_t)f2bf(f1.z) | ((uint32_t)f2bf(f1.w) << 16);
      *(uint4*)(bD + (t + 512) * 16) = u;
    }
  };

  // prologue: 3 sub-stages in flight (12 global_load_lds per wave)
  issueSub(0); issueSub(1); issueSub(2);

  f32x4 acc[8][4];
#pragma unroll
  for (int m = 0; m < 8; ++m)
#pragma unroll
    for (int n = 0; n < 4; ++n) acc[m][n] = (f32x4){0.f, 0.f, 0.f, 0.f};

#pragma unroll 1
  for (int sigma = 0; sigma < 16; ++sigma) {
    int kt = sigma >> 1, s = sigma & 1, buf = kt & 1;
    if constexpr (BF16B) {
      int remain = 15 - sigma;
      __builtin_amdgcn_sched_barrier(0);
      if (remain >= 2)      asm volatile("s_waitcnt vmcnt(8)" ::: "memory");
      else if (remain == 1) asm volatile("s_waitcnt vmcnt(4)" ::: "memory");
      else                  asm volatile("s_waitcnt vmcnt(0)" ::: "memory");
      __builtin_amdgcn_s_barrier();
      __builtin_amdgcn_sched_barrier(0);
    } else {
      __syncthreads();
    }
    const char* aB = smem + buf * 65536 + s * 16384;
    const char* bB = aB + 32768;
    bf16x8 av[8], bv[4];
#pragma unroll
    for (int m = 0; m < 8; ++m) {
      int r = wm * 128 + m * 16 + rl;
      av[m] = *(const bf16x8*)(aB + r * 64 + ((sl ^ ((r >> 1) & 3)) * 16));
    }
#pragma unroll
    for (int n = 0; n < 4; ++n) {
      int r = wn2 * 64 + n * 16 + rl;
      bv[n] = *(const bf16x8*)(bB + r * 64 + ((sl ^ ((r >> 1) & 3)) * 16));
    }
    if (sigma + 3 <= 15) issueSub(sigma + 3);
    __builtin_amdgcn_s_setprio(1);
#pragma unroll
    for (int n = 0; n < 4; ++n)
#pragma unroll
      for (int m = 0; m < 8; ++m)
        acc[m][n] = __builtin_amdgcn_mfma_f32_16x16x32_bf16(av[m], bv[n], acc[m][n], 0, 0, 0);
    __builtin_amdgcn_s_setprio(0);
    if constexpr (BF16B) {
      __builtin_amdgcn_s_barrier();
      __builtin_amdgcn_sched_barrier(0);
    } else {
      __syncthreads();
    }
  }

  // epilogue: out = rawdot, except at (r, label[r]) where the exact f32 dot decides
  float mm = mArr[0];
  float cm = cosf(mm), sm = sinf(mm);
  int rowb = rowA0 + wm * 128, colb = rowB0 + wn2 * 64;
#pragma unroll
  for (int m = 0; m < 8; ++m) {
#pragma unroll
    for (int q = 0; q < 4; ++q) {
      int R = rowb + m * 16 + sl * 4 + q;
      int lab = label[R];
      float nv = norms[R], fv = fixdot[R];
      float* orow = out0 + (size_t)R * OUT_DIM;
#pragma unroll
      for (int n = 0; n < 4; ++n) {
        int Cc = colb + n * 16 + rl;
        float val = acc[m][n][q];
        if (Cc == lab) {
          float c = fv / fmaxf(nv, EPSN);
          val = (c > 0.f) ? nv * (c * cm - sqrtf(fmaxf(1.f - c * c, 0.f)) * sm) : fv;
        }
        orow[Cc] = val;
      }
    }
  }
}

extern "C" void kernel_launch(void* const* d_in, const int* in_sizes, int n_in,
                              void* d_out, int out_size, void* d_ws, size_t ws_size,
                              hipStream_t stream) {
  const float* x = (const float*)d_in[0];
  const int* label = (const int*)d_in[1];
  const float* weight = (const float*)d_in[2];
  const float* mArr = (const float*)d_in[4];  // d_in[3] = s, unused by normfree output

  float* out0 = (float*)d_out;                               // [1024, 64000]
  float* wnOut = out0 + (size_t)B_ROWS * OUT_DIM;            // [64000, 512]

  char* ws = (char*)d_ws;
  float* norms = (float*)ws;                                 // 4 KiB
  float* fixdot = (float*)(ws + 4096);                       // 4 KiB
  unsigned short* xbf = (unsigned short*)(ws + 8192);        // 1 MiB
  unsigned short* wbf = (unsigned short*)(ws + 8192 + 2ull * B_ROWS * IN_DIM);
  size_t need = 8192 + 2ull * B_ROWS * IN_DIM + 2ull * OUT_DIM * IN_DIM;
  bool useBf = ws_size >= need;

  wnorm_kernel<<<OUT_DIM / 4, 256, 0, stream>>>(weight, wnOut, wbf, useBf ? 1 : 0);
  prep_kernel<<<B_ROWS / 4, 256, 0, stream>>>(x, label, wnOut, norms, fixdot, xbf);
  if (useBf)
    gemm8_kernel<true><<<1000, 512, 0, stream>>>(xbf, wbf, wnOut, norms, fixdot,
                                                 label, mArr, out0);
  else
    gemm8_kernel<false><<<1000, 512, 0, stream>>>(xbf, wbf, wnOut, norms, fixdot,
                                                  label, mArr, out0);
}